// Round 1
// baseline (1150.349 us; speedup 1.0000x reference)
//
#include <hip/hip_runtime.h>

// Workspace layout (floats): dinv[N] | hs1[N*32] | agg1[N*32] | hs2[N*64] | agg2[N*64] | vtmp[N]
// Total = 194*N floats = 77.6 MB for N=100000.

__global__ void k_zero_out(float* out, int n) {
    int i = blockIdx.x * blockDim.x + threadIdx.x;
    if (i < n) out[i] = 0.0f;
}

__global__ void k_fill1(float* p, int n) {
    int i = blockIdx.x * blockDim.x + threadIdx.x;
    if (i < n) p[i] = 1.0f;
}

__global__ void k_count(const int* __restrict__ dst, float* __restrict__ deg, int E) {
    int e = blockIdx.x * blockDim.x + threadIdx.x;
    if (e < E) atomicAdd(&deg[dst[e]], 1.0f);
}

__global__ void k_rsqrt_inplace(float* p, int n) {
    int i = blockIdx.x * blockDim.x + threadIdx.x;
    if (i < n) p[i] = rsqrtf(p[i]);
}

// h = x @ W1 (N x 128 @ 128 x 32); hs1 = h*dinv; agg1 = h*dinv^2 + b1 (self-loop + bias folded in)
__global__ __launch_bounds__(256) void k_gemm1(
    const float* __restrict__ x, const float* __restrict__ W,
    const float* __restrict__ b, const float* __restrict__ dinv,
    float* __restrict__ hs1, float* __restrict__ agg1, int N)
{
    __shared__ float Wl[128 * 32];   // 16 KB
    __shared__ float Xl[8 * 132];    // 8 rows, +4 pad per row (16B-aligned rows: 528B)
    const int tid = threadIdx.x;
    for (int i = tid; i < 128 * 32; i += 256) Wl[i] = W[i];
    const int node0 = blockIdx.x * 8;
    {
        int r = tid >> 5, c4 = tid & 31;     // 32 threads/row, each loads one float4
        int node = node0 + r;
        float4 v = make_float4(0.f, 0.f, 0.f, 0.f);
        if (node < N) v = ((const float4*)(x + (size_t)node * 128))[c4];
        *(float4*)&Xl[r * 132 + c4 * 4] = v;
    }
    __syncthreads();
    const int row = tid >> 5, f = tid & 31;  // 8 nodes x 32 features
    float acc = 0.f;
#pragma unroll
    for (int k = 0; k < 128; k += 4) {
        float4 xv = *(const float4*)&Xl[row * 132 + k];  // broadcast within wave
        acc += xv.x * Wl[(k + 0) * 32 + f];
        acc += xv.y * Wl[(k + 1) * 32 + f];
        acc += xv.z * Wl[(k + 2) * 32 + f];
        acc += xv.w * Wl[(k + 3) * 32 + f];
    }
    const int node = node0 + row;
    if (node < N) {
        float dv = dinv[node];
        size_t o = (size_t)node * 32 + f;
        hs1[o]  = acc * dv;
        agg1[o] = acc * dv * dv + b[f];
    }
}

// For each edge e: agg1[dst] += hs1[src] * dinv[dst]   (hs1 already pre-scaled by dinv[src])
__global__ void k_edge1(const int* __restrict__ ei, const float* __restrict__ hs1,
                        const float* __restrict__ dinv, float* __restrict__ agg1, int E)
{
    long long tid = (long long)blockIdx.x * blockDim.x + threadIdx.x;
    int e = (int)(tid >> 5);
    int f = (int)(tid & 31);
    if (e < E) {
        int s = ei[e], d = ei[E + e];
        float w = hs1[(size_t)s * 32 + f] * dinv[d];
        atomicAdd(&agg1[(size_t)d * 32 + f], w);
    }
}

// z1 = relu(agg1) (N x 32) @ W2 (32 x 64); hs2 = h*dinv; agg2 = h*dinv^2 + b2
__global__ __launch_bounds__(256) void k_gemm2(
    const float* __restrict__ agg1, const float* __restrict__ W,
    const float* __restrict__ b, const float* __restrict__ dinv,
    float* __restrict__ hs2, float* __restrict__ agg2, int N)
{
    __shared__ float Wl[32 * 64];  // 8 KB
    __shared__ float Zl[4 * 36];   // 4 rows, +4 pad (144B rows, 16B aligned)
    const int tid = threadIdx.x;
    for (int i = tid; i < 32 * 64; i += 256) Wl[i] = W[i];
    const int node0 = blockIdx.x * 4;
    if (tid < 128) {
        int r = tid >> 5, c = tid & 31;
        int node = node0 + r;
        float v = 0.f;
        if (node < N) v = fmaxf(agg1[(size_t)node * 32 + c], 0.f);
        Zl[r * 36 + c] = v;
    }
    __syncthreads();
    const int row = tid >> 6, f = tid & 63;  // 4 nodes x 64 features; whole wave = one node
    float acc = 0.f;
#pragma unroll
    for (int k = 0; k < 32; k += 4) {
        float4 zv = *(const float4*)&Zl[row * 36 + k];  // broadcast
        acc += zv.x * Wl[(k + 0) * 64 + f];
        acc += zv.y * Wl[(k + 1) * 64 + f];
        acc += zv.z * Wl[(k + 2) * 64 + f];
        acc += zv.w * Wl[(k + 3) * 64 + f];
    }
    int node = node0 + row;
    if (node < N) {
        float dv = dinv[node];
        size_t o = (size_t)node * 64 + f;
        hs2[o]  = acc * dv;
        agg2[o] = acc * dv * dv + b[f];
    }
}

__global__ void k_edge2(const int* __restrict__ ei, const float* __restrict__ hs2,
                        const float* __restrict__ dinv, float* __restrict__ agg2, int E)
{
    long long tid = (long long)blockIdx.x * blockDim.x + threadIdx.x;
    int e = (int)(tid >> 6);
    int f = (int)(tid & 63);
    if (e < E) {
        int s = ei[e], d = ei[E + e];
        float w = hs2[(size_t)s * 64 + f] * dinv[d];
        atomicAdd(&agg2[(size_t)d * 64 + f], w);
    }
}

// Per node: z2 = relu(agg2[node]); t = relu(z2 @ Wm1 + bm1); v = t @ Wm2 + bm2. One wave per node.
__global__ __launch_bounds__(256) void k_mlp(
    const float* __restrict__ agg2, const float* __restrict__ Wm1,
    const float* __restrict__ bm1, const float* __restrict__ Wm2,
    const float* __restrict__ bm2, float* __restrict__ vout, int N)
{
    __shared__ float Wl[64 * 64];  // 16 KB, natural [k][f]
    __shared__ float W2l[64];
    __shared__ float Zl[4][64];
    const int tid = threadIdx.x;
    for (int i = tid; i < 64 * 64; i += 256) Wl[i] = Wm1[i];
    if (tid < 64) W2l[tid] = Wm2[tid];
    const int wid = tid >> 6, lane = tid & 63;
    const int node = blockIdx.x * 4 + wid;
    float zv = 0.f;
    if (node < N) zv = fmaxf(agg2[(size_t)node * 64 + lane], 0.f);
    Zl[wid][lane] = zv;
    __syncthreads();
    float t = bm1[lane];
#pragma unroll
    for (int k = 0; k < 64; k += 4) {
        float4 z4 = *(const float4*)&Zl[wid][k];  // broadcast
        t += z4.x * Wl[(k + 0) * 64 + lane];
        t += z4.y * Wl[(k + 1) * 64 + lane];
        t += z4.z * Wl[(k + 2) * 64 + lane];
        t += z4.w * Wl[(k + 3) * 64 + lane];
    }
    t = fmaxf(t, 0.f);
    float val = t * W2l[lane];
#pragma unroll
    for (int off = 32; off > 0; off >>= 1) val += __shfl_down(val, off, 64);
    if (lane == 0 && node < N) vout[node] = val + bm2[0];
}

// out[g] = mean of v over each num_nodes segment
__global__ void k_reduce(const float* __restrict__ v, const int* __restrict__ num_nodes_p,
                         float* out, int N, int n_graphs)
{
    __shared__ float acc[32];
    int tid = threadIdx.x;
    if (tid < n_graphs) acc[tid] = 0.f;
    __syncthreads();
    int i = blockIdx.x * blockDim.x + tid;
    int nn = num_nodes_p[0];
    if (i < N) {
        int g = i / nn;
        if (g < n_graphs) atomicAdd(&acc[g], v[i]);
    }
    __syncthreads();
    if (tid < n_graphs) atomicAdd(&out[tid], acc[tid] / (float)nn);
}

extern "C" void kernel_launch(void* const* d_in, const int* in_sizes, int n_in,
                              void* d_out, int out_size, void* d_ws, size_t ws_size,
                              hipStream_t stream)
{
    const float* x   = (const float*)d_in[0];
    const float* W1  = (const float*)d_in[1];
    const float* b1  = (const float*)d_in[2];
    const float* W2  = (const float*)d_in[3];
    const float* b2  = (const float*)d_in[4];
    const float* Wm1 = (const float*)d_in[5];
    const float* bm1 = (const float*)d_in[6];
    const float* Wm2 = (const float*)d_in[7];
    const float* bm2 = (const float*)d_in[8];
    const int*   ei  = (const int*)d_in[9];
    const int*   nn  = (const int*)d_in[10];
    const int N = in_sizes[0] / 128;
    const int E = in_sizes[9] / 2;
    float* out = (float*)d_out;

    float* ws   = (float*)d_ws;
    float* dinv = ws;                 ws += N;
    float* hs1  = ws;                 ws += (size_t)N * 32;
    float* agg1 = ws;                 ws += (size_t)N * 32;
    float* hs2  = ws;                 ws += (size_t)N * 64;
    float* agg2 = ws;                 ws += (size_t)N * 64;
    float* vtmp = ws;                 ws += N;

    k_zero_out<<<1, 64, 0, stream>>>(out, out_size);
    k_fill1<<<(N + 255) / 256, 256, 0, stream>>>(dinv, N);
    k_count<<<(E + 255) / 256, 256, 0, stream>>>(ei + E, dinv, E);
    k_rsqrt_inplace<<<(N + 255) / 256, 256, 0, stream>>>(dinv, N);
    k_gemm1<<<(N + 7) / 8, 256, 0, stream>>>(x, W1, b1, dinv, hs1, agg1, N);
    {
        long long t = (long long)E * 32;
        k_edge1<<<(unsigned)((t + 255) / 256), 256, 0, stream>>>(ei, hs1, dinv, agg1, E);
    }
    k_gemm2<<<(N + 3) / 4, 256, 0, stream>>>(agg1, W2, b2, dinv, hs2, agg2, N);
    {
        long long t = (long long)E * 64;
        k_edge2<<<(unsigned)((t + 255) / 256), 256, 0, stream>>>(ei, hs2, dinv, agg2, E);
    }
    k_mlp<<<(N + 3) / 4, 256, 0, stream>>>(agg2, Wm1, bm1, Wm2, bm2, vtmp, N);
    k_reduce<<<(N + 255) / 256, 256, 0, stream>>>(vtmp, nn, out, N, out_size);
}

// Round 2
// 772.175 us; speedup vs baseline: 1.4898x; 1.4898x over previous
//
#include <hip/hip_runtime.h>

// ---------------------------------------------------------------------------
// CriticNetwork: 2x GCNConv (relu) + MLP head + per-graph mean.
// Round 2: replace 240M float atomics (edge scatter) with on-the-fly CSR
// (counting sort by dst, built once, reused for both layers) + gather-reduce.
// Self-loop + bias folded into aggregation: agg[n] = dinv[n]*(hs[n] + sum_{s->n} hs[s]) + b
// where hs = (x@W)*dinv (pre-scaled by source dinv).
// ---------------------------------------------------------------------------

__global__ void k_zero_out(float* out, int n) {
    int i = blockIdx.x * blockDim.x + threadIdx.x;
    if (i < n) out[i] = 0.0f;
}

__global__ void k_zero_int(int* p, int n) {
    int i = blockIdx.x * blockDim.x + threadIdx.x;
    if (i < n) p[i] = 0;
}

__global__ void k_hist(const int* __restrict__ dst, int* __restrict__ deg, int E) {
    int e = blockIdx.x * blockDim.x + threadIdx.x;
    if (e < E) atomicAdd(&deg[dst[e]], 1);
}

// dinv = rsqrt(1 + indeg)   (the +1 is the self-loop)
__global__ void k_dinv(const int* __restrict__ deg, float* __restrict__ dinv, int n) {
    int i = blockIdx.x * blockDim.x + threadIdx.x;
    if (i < n) dinv[i] = rsqrtf(1.0f + (float)deg[i]);
}

// Block-local inclusive scan of deg -> row_start[i+1]; block totals -> blockSums
__global__ __launch_bounds__(256) void k_scan1(const int* __restrict__ deg, int* __restrict__ row_start,
                                               int* __restrict__ blockSums, int N) {
    __shared__ int sh[256];
    int t = threadIdx.x;
    int i = blockIdx.x * 256 + t;
    int v = (i < N) ? deg[i] : 0;
    sh[t] = v;
    __syncthreads();
    for (int off = 1; off < 256; off <<= 1) {
        int tv = (t >= off) ? sh[t - off] : 0;
        __syncthreads();
        sh[t] += tv;
        __syncthreads();
    }
    if (i < N) row_start[i + 1] = sh[t];
    if (t == 255) blockSums[blockIdx.x] = sh[255];
}

// Exclusive scan of blockSums in a single 512-thread block (nb <= 512)
__global__ __launch_bounds__(512) void k_scan2(int* bs, int nb) {
    __shared__ int sh[512];
    int t = threadIdx.x;
    int v = (t < nb) ? bs[t] : 0;
    sh[t] = v;
    __syncthreads();
    for (int off = 1; off < 512; off <<= 1) {
        int tv = (t >= off) ? sh[t - off] : 0;
        __syncthreads();
        sh[t] += tv;
        __syncthreads();
    }
    if (t < nb) bs[t] = sh[t] - v;  // exclusive
}

__global__ void k_scan3(int* __restrict__ row_start, const int* __restrict__ bs, int N) {
    int i = blockIdx.x * blockDim.x + threadIdx.x;
    if (i < N) row_start[i + 1] += bs[i >> 8];
    if (i == 0) row_start[0] = 0;
}

__global__ void k_copy_int(int* __restrict__ d, const int* __restrict__ s, int n) {
    int i = blockIdx.x * blockDim.x + threadIdx.x;
    if (i < n) d[i] = s[i];
}

// Counting-sort scatter: esrc_sorted grouped by dst
__global__ void k_scatter(const int* __restrict__ ei, int* __restrict__ cursor,
                          int* __restrict__ esrc, int E) {
    int e = blockIdx.x * blockDim.x + threadIdx.x;
    if (e < E) {
        int d = ei[E + e];
        int pos = atomicAdd(&cursor[d], 1);
        esrc[pos] = ei[e];
    }
}

// hs1 = (x @ W1) * dinv   (N x 128 @ 128 x 32)
__global__ __launch_bounds__(256) void k_gemm1(
    const float* __restrict__ x, const float* __restrict__ W,
    const float* __restrict__ dinv, float* __restrict__ hs1, int N)
{
    __shared__ float Wl[128 * 32];   // 16 KB
    __shared__ float Xl[8 * 132];
    const int tid = threadIdx.x;
    for (int i = tid; i < 128 * 32; i += 256) Wl[i] = W[i];
    const int node0 = blockIdx.x * 8;
    {
        int r = tid >> 5, c4 = tid & 31;
        int node = node0 + r;
        float4 v = make_float4(0.f, 0.f, 0.f, 0.f);
        if (node < N) v = ((const float4*)(x + (size_t)node * 128))[c4];
        *(float4*)&Xl[r * 132 + c4 * 4] = v;
    }
    __syncthreads();
    const int row = tid >> 5, f = tid & 31;
    float acc = 0.f;
#pragma unroll
    for (int k = 0; k < 128; k += 4) {
        float4 xv = *(const float4*)&Xl[row * 132 + k];
        acc += xv.x * Wl[(k + 0) * 32 + f];
        acc += xv.y * Wl[(k + 1) * 32 + f];
        acc += xv.z * Wl[(k + 2) * 32 + f];
        acc += xv.w * Wl[(k + 3) * 32 + f];
    }
    const int node = node0 + row;
    if (node < N) hs1[(size_t)node * 32 + f] = acc * dinv[node];
}

// hs2 = (relu(agg1) @ W2) * dinv   (N x 32 @ 32 x 64)
__global__ __launch_bounds__(256) void k_gemm2(
    const float* __restrict__ agg1, const float* __restrict__ W,
    const float* __restrict__ dinv, float* __restrict__ hs2, int N)
{
    __shared__ float Wl[32 * 64];
    __shared__ float Zl[4 * 36];
    const int tid = threadIdx.x;
    for (int i = tid; i < 32 * 64; i += 256) Wl[i] = W[i];
    const int node0 = blockIdx.x * 4;
    if (tid < 128) {
        int r = tid >> 5, c = tid & 31;
        int node = node0 + r;
        float v = 0.f;
        if (node < N) v = fmaxf(agg1[(size_t)node * 32 + c], 0.f);
        Zl[r * 36 + c] = v;
    }
    __syncthreads();
    const int row = tid >> 6, f = tid & 63;
    float acc = 0.f;
#pragma unroll
    for (int k = 0; k < 32; k += 4) {
        float4 zv = *(const float4*)&Zl[row * 36 + k];
        acc += zv.x * Wl[(k + 0) * 64 + f];
        acc += zv.y * Wl[(k + 1) * 64 + f];
        acc += zv.z * Wl[(k + 2) * 64 + f];
        acc += zv.w * Wl[(k + 3) * 64 + f];
    }
    int node = node0 + row;
    if (node < N) hs2[(size_t)node * 64 + f] = acc * dinv[node];
}

// CSR gather-reduce: out[n,f] = dinv[n] * (hs[n,f] + sum_{e in row n} hs[esrc[e], f]) + b[f]
template <int F>
__global__ __launch_bounds__(256) void k_agg(
    const float* __restrict__ hs, const float* __restrict__ b,
    const float* __restrict__ dinv, const int* __restrict__ row_start,
    const int* __restrict__ esrc, float* __restrict__ out, int N)
{
    const int tid = threadIdx.x;
    const int per_block = 256 / F;
    const int sub = tid / F, f = tid % F;
    const int n = blockIdx.x * per_block + sub;
    if (n >= N) return;
    const int beg = row_start[n], end = row_start[n + 1];
    float acc = hs[(size_t)n * F + f];     // self-loop term (pre-division by dinv)
    int e = beg;
    for (; e + 3 < end; e += 4) {
        int s0 = esrc[e], s1 = esrc[e + 1], s2 = esrc[e + 2], s3 = esrc[e + 3];
        float a0 = hs[(size_t)s0 * F + f];
        float a1 = hs[(size_t)s1 * F + f];
        float a2 = hs[(size_t)s2 * F + f];
        float a3 = hs[(size_t)s3 * F + f];
        acc += a0 + a1 + a2 + a3;
    }
    for (; e < end; ++e) acc += hs[(size_t)esrc[e] * F + f];
    out[(size_t)n * F + f] = dinv[n] * acc + b[f];
}

// ---- fallback (atomic) path, used only if ws_size too small for CSR ----
template <int F>
__global__ void k_agg_init(const float* __restrict__ hs, const float* __restrict__ b,
                           const float* __restrict__ dinv, float* __restrict__ agg, int N)
{
    long long t = (long long)blockIdx.x * blockDim.x + threadIdx.x;
    int n = (int)(t / F), f = (int)(t % F);
    if (n < N) agg[(size_t)n * F + f] = hs[(size_t)n * F + f] * dinv[n] + b[f];
}

template <int F>
__global__ void k_edge_atomic(const int* __restrict__ ei, const float* __restrict__ hs,
                              const float* __restrict__ dinv, float* __restrict__ agg, int E)
{
    long long tid = (long long)blockIdx.x * blockDim.x + threadIdx.x;
    int e = (int)(tid / F), f = (int)(tid % F);
    if (e < E) {
        int s = ei[e], d = ei[E + e];
        atomicAdd(&agg[(size_t)d * F + f], hs[(size_t)s * F + f] * dinv[d]);
    }
}
// -----------------------------------------------------------------------

// Per node: z2 = relu(agg2); t = relu(z2 @ Wm1 + bm1); v = t @ Wm2 + bm2
__global__ __launch_bounds__(256) void k_mlp(
    const float* __restrict__ agg2, const float* __restrict__ Wm1,
    const float* __restrict__ bm1, const float* __restrict__ Wm2,
    const float* __restrict__ bm2, float* __restrict__ vout, int N)
{
    __shared__ float Wl[64 * 64];
    __shared__ float W2l[64];
    __shared__ float Zl[4][64];
    const int tid = threadIdx.x;
    for (int i = tid; i < 64 * 64; i += 256) Wl[i] = Wm1[i];
    if (tid < 64) W2l[tid] = Wm2[tid];
    const int wid = tid >> 6, lane = tid & 63;
    const int node = blockIdx.x * 4 + wid;
    float zv = 0.f;
    if (node < N) zv = fmaxf(agg2[(size_t)node * 64 + lane], 0.f);
    Zl[wid][lane] = zv;
    __syncthreads();
    float t = bm1[lane];
#pragma unroll
    for (int k = 0; k < 64; k += 4) {
        float4 z4 = *(const float4*)&Zl[wid][k];
        t += z4.x * Wl[(k + 0) * 64 + lane];
        t += z4.y * Wl[(k + 1) * 64 + lane];
        t += z4.z * Wl[(k + 2) * 64 + lane];
        t += z4.w * Wl[(k + 3) * 64 + lane];
    }
    t = fmaxf(t, 0.f);
    float val = t * W2l[lane];
#pragma unroll
    for (int off = 32; off > 0; off >>= 1) val += __shfl_down(val, off, 64);
    if (lane == 0 && node < N) vout[node] = val + bm2[0];
}

__global__ void k_reduce(const float* __restrict__ v, const int* __restrict__ num_nodes_p,
                         float* out, int N, int n_graphs)
{
    __shared__ float acc[32];
    int tid = threadIdx.x;
    if (tid < n_graphs) acc[tid] = 0.f;
    __syncthreads();
    int i = blockIdx.x * blockDim.x + tid;
    int nn = num_nodes_p[0];
    if (i < N) {
        int g = i / nn;
        if (g < n_graphs) atomicAdd(&acc[g], v[i]);
    }
    __syncthreads();
    if (tid < n_graphs) atomicAdd(&out[tid], acc[tid] / (float)nn);
}

extern "C" void kernel_launch(void* const* d_in, const int* in_sizes, int n_in,
                              void* d_out, int out_size, void* d_ws, size_t ws_size,
                              hipStream_t stream)
{
    const float* x   = (const float*)d_in[0];
    const float* W1  = (const float*)d_in[1];
    const float* b1  = (const float*)d_in[2];
    const float* W2  = (const float*)d_in[3];
    const float* b2  = (const float*)d_in[4];
    const float* Wm1 = (const float*)d_in[5];
    const float* bm1 = (const float*)d_in[6];
    const float* Wm2 = (const float*)d_in[7];
    const float* bm2 = (const float*)d_in[8];
    const int*   ei  = (const int*)d_in[9];
    const int*   nn  = (const int*)d_in[10];
    const int N = in_sizes[0] / 128;
    const int E = in_sizes[9] / 2;
    float* out = (float*)d_out;

    const size_t Ns = (size_t)N;
    const size_t csr_elems = (Ns + 1) + (size_t)E + Ns + 192 * Ns;  // row_start + esrc + dinv + B
    const bool use_csr = ws_size >= csr_elems * sizeof(int) && N <= 131072;

    k_zero_out<<<1, 64, 0, stream>>>(out, out_size);

    if (use_csr) {
        int*   row_start = (int*)d_ws;                  // N+1
        int*   esrc      = row_start + (N + 1);         // E
        float* dinv      = (float*)(esrc + E);          // N
        float* B         = dinv + N;                    // 192N floats
        float* hs1  = B;
        float* agg1 = B + 32 * Ns;
        float* hs2  = B + 64 * Ns;
        float* agg2 = B + 128 * Ns;
        float* vtmp = B;                                // aliases hs1 (free at MLP time)
        // CSR-build temps alias the hs1 region (all dead before k_gemm1 writes hs1)
        int* deg       = (int*)B;                       // N
        int* cursor    = (int*)B + N;                   // N
        int* blockSums = (int*)B + 2 * N;               // nb <= 512

        const int nb = (N + 255) / 256;
        k_zero_int<<<nb, 256, 0, stream>>>(deg, N);
        k_hist<<<(E + 255) / 256, 256, 0, stream>>>(ei + E, deg, E);
        k_dinv<<<nb, 256, 0, stream>>>(deg, dinv, N);
        k_scan1<<<nb, 256, 0, stream>>>(deg, row_start, blockSums, N);
        k_scan2<<<1, 512, 0, stream>>>(blockSums, nb);
        k_scan3<<<nb, 256, 0, stream>>>(row_start, blockSums, N);
        k_copy_int<<<nb, 256, 0, stream>>>(cursor, row_start, N);
        k_scatter<<<(E + 255) / 256, 256, 0, stream>>>(ei, cursor, esrc, E);

        k_gemm1<<<(N + 7) / 8, 256, 0, stream>>>(x, W1, dinv, hs1, N);
        k_agg<32><<<(N + 7) / 8, 256, 0, stream>>>(hs1, b1, dinv, row_start, esrc, agg1, N);
        k_gemm2<<<(N + 3) / 4, 256, 0, stream>>>(agg1, W2, dinv, hs2, N);
        k_agg<64><<<(N + 3) / 4, 256, 0, stream>>>(hs2, b2, dinv, row_start, esrc, agg2, N);
        k_mlp<<<(N + 3) / 4, 256, 0, stream>>>(agg2, Wm1, bm1, Wm2, bm2, vtmp, N);
        k_reduce<<<nb, 256, 0, stream>>>(vtmp, nn, out, N, out_size);
    } else {
        // fallback: atomic scatter path (round-0 structure), 193N floats
        float* dinv = (float*)d_ws;                     // N
        float* B    = dinv + N;
        float* hs1  = B;
        float* agg1 = B + 32 * Ns;
        float* hs2  = B + 64 * Ns;
        float* agg2 = B + 128 * Ns;
        float* vtmp = B;
        int*   deg  = (int*)B;                          // aliases hs1, dead before gemm1

        const int nb = (N + 255) / 256;
        k_zero_int<<<nb, 256, 0, stream>>>(deg, N);
        k_hist<<<(E + 255) / 256, 256, 0, stream>>>(ei + E, deg, E);
        k_dinv<<<nb, 256, 0, stream>>>(deg, dinv, N);

        k_gemm1<<<(N + 7) / 8, 256, 0, stream>>>(x, W1, dinv, hs1, N);
        {
            long long t = (long long)N * 32;
            k_agg_init<32><<<(unsigned)((t + 255) / 256), 256, 0, stream>>>(hs1, b1, dinv, agg1, N);
            t = (long long)E * 32;
            k_edge_atomic<32><<<(unsigned)((t + 255) / 256), 256, 0, stream>>>(ei, hs1, dinv, agg1, E);
        }
        k_gemm2<<<(N + 3) / 4, 256, 0, stream>>>(agg1, W2, dinv, hs2, N);
        {
            long long t = (long long)N * 64;
            k_agg_init<64><<<(unsigned)((t + 255) / 256), 256, 0, stream>>>(hs2, b2, dinv, agg2, N);
            t = (long long)E * 64;
            k_edge_atomic<64><<<(unsigned)((t + 255) / 256), 256, 0, stream>>>(ei, hs2, dinv, agg2, E);
        }
        k_mlp<<<(N + 3) / 4, 256, 0, stream>>>(agg2, Wm1, bm1, Wm2, bm2, vtmp, N);
        k_reduce<<<nb, 256, 0, stream>>>(vtmp, nn, out, N, out_size);
    }
}